// Round 6
// baseline (38.961 us; speedup 1.0000x reference)
//
#include <hip/hip_runtime.h>
#include <hip/hip_bf16.h>

// Problem constants
#define M_ROWS   1792                 // 7 * 256 softpool rows
#define KDIM     512
#define OUT_FEAT_SZ (M_ROWS*1024)     // 1835008
#define OUT_HAT_SZ  (M_ROWS*512)      // 917504

typedef __attribute__((ext_vector_type(8))) __bf16 bf16x8;
typedef __attribute__((ext_vector_type(4))) float  f32x4;
typedef __attribute__((ext_vector_type(8))) unsigned short ushort8v;

__device__ __forceinline__ unsigned short f2bf(float f) {
    union { float f; unsigned int u; } v; v.f = f;
    unsigned int r = v.u + 0x7fffu + ((v.u >> 16) & 1u);   // RNE
    return (unsigned short)(r >> 16);
}

__device__ __forceinline__ void load_lds16(const float* g, float* l) {
    __builtin_amdgcn_global_load_lds(
        (const __attribute__((address_space(1))) void*)g,
        (__attribute__((address_space(3))) void*)l, 16, 0, 0);
}

// K1: softpool3d (4,2,2)/(2,2,2) rows (blocks 0..1791) + weight f32->bf16 cvt
// (blocks 1792..1919). blockIdx.y = tensor side.
// Softpool via global_load_lds: loads are fire-and-forget (0 VGPRs), so each
// wave keeps 8 KB in flight regardless of the compiler's register schedule
// (rounds 3-5 were stuck at 1-2 reg-loads in flight -> ~3 TB/s L3).
__global__ __launch_bounds__(256) void sp_k(
    const float* __restrict__ x, const float* __restrict__ y,
    const float* __restrict__ wv, const float* __restrict__ wt,
    float* __restrict__ xsp, float* __restrict__ ysp,
    unsigned short* __restrict__ wvb, unsigned short* __restrict__ wtb)
{
    const int side = blockIdx.y;
    if (blockIdx.x >= M_ROWS) {
        // ---- weight cvt: 128 blocks x 256 thr x 8 elems = 262144
        int blk = blockIdx.x - M_ROWS;
        const float* s = side ? wt : wv;
        unsigned short* d = side ? wtb : wvb;
        int i = (blk * 256 + threadIdx.x) * 8;
        float4 v0 = *reinterpret_cast<const float4*>(s + i);
        float4 v1 = *reinterpret_cast<const float4*>(s + i + 4);
        ushort8v o;
        o[0]=f2bf(v0.x); o[1]=f2bf(v0.y); o[2]=f2bf(v0.z); o[3]=f2bf(v0.w);
        o[4]=f2bf(v1.x); o[5]=f2bf(v1.y); o[6]=f2bf(v1.z); o[7]=f2bf(v1.w);
        *reinterpret_cast<ushort8v*>(d + i) = o;
        return;
    }
    const float* in  = side ? y   : x;
    float*       out = side ? ysp : xsp;
    const int r  = blockIdx.x;
    const int bp = r >> 8;        // b' 0..6
    const int lp = r & 255;       // l'

    __shared__ float buf[8192];   // 8 taps x 1024 cols (32 KB)

    const int tid  = threadIdx.x;
    const int wav  = tid >> 6;    // 0..3
    const int lane = tid & 63;

    // ---- stage: 8 taps x 4 KB, wave w loads segment w of each tap
    const float* rowbase = in + ((size_t)(2*bp) * 512 + 2*lp) * 1024;
    #pragma unroll
    for (int t = 0; t < 8; ++t) {
        int i = t >> 1, j = t & 1;
        const float* gp = rowbase + ((size_t)(i*512 + j)) * 1024 + wav*256 + lane*4;
        load_lds16(gp, &buf[t*1024 + wav*256]);   // LDS dst: base + lane*16
    }
    asm volatile("s_waitcnt vmcnt(0)" ::: "memory");
    __syncthreads();

    // ---- compute: thread u owns d' pair (2u, 2u+1) = input cols 4u..4u+3
    const int u = tid;
    float num0=0.f, den0=0.f, num1=0.f, den1=0.f;
    #pragma unroll
    for (int t = 0; t < 8; ++t) {
        float4 v = *reinterpret_cast<const float4*>(&buf[t*1024 + 4*u]);
        float e0=__expf(v.x), e1=__expf(v.y), e2=__expf(v.z), e3=__expf(v.w);
        num0 += e0*v.x + e1*v.y;  den0 += e0 + e1;
        num1 += e2*v.z + e3*v.w;  den1 += e2 + e3;
    }
    *reinterpret_cast<float2*>(out + (size_t)r*512 + 2*u) =
        make_float2(num0/den0, num1/den1);
}

// K2: C = A @ W^T + bias (+ residual A, side 0), row-softmax N=512, write hat
// + scaled feature half. 16-row tiles (224 blocks/side), 1024 thr / 16 waves;
// wave w owns cols [w*32,w*32+32); B register-double-buffered 2 ks ahead.
__global__ __launch_bounds__(1024) void gemm_sm_k(
    const float* __restrict__ xsp, const float* __restrict__ ysp,
    const unsigned short* __restrict__ wvb, const unsigned short* __restrict__ wtb,
    const float* __restrict__ bv, const float* __restrict__ bt,
    const float* __restrict__ wvec, float* __restrict__ d_out)
{
    const int side = blockIdx.y;
    const float* A           = side ? ysp : xsp;
    const unsigned short* B  = side ? wtb : wvb;
    const float* bias        = side ? bt  : bv;
    const int mbase = blockIdx.x * 16;

    __shared__ unsigned short tA[16 * 520];  // bf16 A tile, padded
    __shared__ float resl[16 * 516];         // f32 A copy (residual) -> logits

    const int tid = threadIdx.x;

    // ---- stage A: 16x512 f32 -> {bf16 tA, f32 resl}
    {
        const float* Ab = A + (size_t)mbase * KDIM;
        #pragma unroll
        for (int rr = 0; rr < 2; ++rr) {
            int f4  = tid + rr*1024;           // 0..2047
            float4 v = reinterpret_cast<const float4*>(Ab)[f4];
            int row = f4 >> 7;
            int col = (f4 & 127) << 2;
            ushort4 o; o.x=f2bf(v.x); o.y=f2bf(v.y); o.z=f2bf(v.z); o.w=f2bf(v.w);
            *reinterpret_cast<ushort4*>(&tA[row*520 + col]) = o;
            *reinterpret_cast<float4*>(&resl[row*516 + col]) = v;
        }
    }
    __syncthreads();

    const int lane = tid & 63;
    const int w    = tid >> 6;       // 0..15
    const int arow = lane & 15;
    const int kq   = lane >> 4;      // 0..3
    const int nb   = w * 32;

    f32x4 acc0 = (f32x4){0.f,0.f,0.f,0.f};
    f32x4 acc1 = (f32x4){0.f,0.f,0.f,0.f};

    const unsigned short* B0 = B + (size_t)(nb      + arow) * KDIM + kq*8;
    const unsigned short* B1 = B + (size_t)(nb + 16 + arow) * KDIM + kq*8;
    bf16x8 b0a = *reinterpret_cast<const bf16x8*>(B0);
    bf16x8 b1a = *reinterpret_cast<const bf16x8*>(B1);
    bf16x8 b0b = *reinterpret_cast<const bf16x8*>(B0 + 32);
    bf16x8 b1b = *reinterpret_cast<const bf16x8*>(B1 + 32);

    #pragma unroll
    for (int ks = 0; ks < 16; ++ks) {
        bf16x8 af = *reinterpret_cast<const bf16x8*>(&tA[arow*520 + ks*32 + kq*8]);
        bf16x8 c0 = b0a, c1 = b1a;
        b0a = b0b; b1a = b1b;
        if (ks < 14) {
            b0b = *reinterpret_cast<const bf16x8*>(B0 + (ks+2)*32);
            b1b = *reinterpret_cast<const bf16x8*>(B1 + (ks+2)*32);
        }
        acc0 = __builtin_amdgcn_mfma_f32_16x16x32_bf16(af, c0, acc0, 0, 0, 0);
        acc1 = __builtin_amdgcn_mfma_f32_16x16x32_bf16(af, c1, acc1, 0, 0, 0);
    }

    // ---- epilogue: logits = acc + bias (+ residual side 0), in-place
    #pragma unroll
    for (int t = 0; t < 2; ++t) {
        int n = nb + t*16 + arow;
        float bn = bias[n];
        f32x4 a = t ? acc1 : acc0;
        #pragma unroll
        for (int i = 0; i < 4; ++i) {
            int row = kq*4 + i;    // C/D: col=lane&15, row=(lane>>4)*4+i
            float vv = a[i] + bn;
            if (side == 0) vv += resl[row*516 + n];
            resl[row*516 + n] = vv;
        }
    }
    __syncthreads();

    // ---- softmax: wave w handles row w (full 512 cols, 8 per lane)
    float ew0 = __expf(wvec[0]), ew1 = __expf(wvec[1]);
    float wsc = (side ? ew1 : ew0) / (ew0 + ew1);
    float* feat = d_out;
    float* hat  = d_out + OUT_FEAT_SZ + (size_t)side * OUT_HAT_SZ;

    {
        int m = mbase + w;
        const float* lp = &resl[w*516 + lane*8];
        float4 v0 = *reinterpret_cast<const float4*>(lp);
        float4 v1 = *reinterpret_cast<const float4*>(lp + 4);
        float mx = fmaxf(fmaxf(fmaxf(v0.x,v0.y), fmaxf(v0.z,v0.w)),
                         fmaxf(fmaxf(v1.x,v1.y), fmaxf(v1.z,v1.w)));
        #pragma unroll
        for (int s = 32; s; s >>= 1) mx = fmaxf(mx, __shfl_xor(mx, s));
        float e0=__expf(v0.x-mx), e1=__expf(v0.y-mx), e2=__expf(v0.z-mx), e3=__expf(v0.w-mx);
        float e4=__expf(v1.x-mx), e5=__expf(v1.y-mx), e6=__expf(v1.z-mx), e7=__expf(v1.w-mx);
        float sum = ((e0+e1)+(e2+e3)) + ((e4+e5)+(e6+e7));
        #pragma unroll
        for (int s = 32; s; s >>= 1) sum += __shfl_xor(sum, s);
        float inv = 1.f / sum;
        float4 p0 = {e0*inv, e1*inv, e2*inv, e3*inv};
        float4 p1 = {e4*inv, e5*inv, e6*inv, e7*inv};
        *reinterpret_cast<float4*>(&hat[(size_t)m*512 + lane*8])     = p0;
        *reinterpret_cast<float4*>(&hat[(size_t)m*512 + lane*8 + 4]) = p1;
        float4 f0 = {p0.x*wsc, p0.y*wsc, p0.z*wsc, p0.w*wsc};
        float4 f1 = {p1.x*wsc, p1.y*wsc, p1.z*wsc, p1.w*wsc};
        size_t fo = (size_t)m*1024 + side*512 + lane*8;
        *reinterpret_cast<float4*>(&feat[fo])     = f0;
        *reinterpret_cast<float4*>(&feat[fo + 4]) = f1;
    }
}

extern "C" void kernel_launch(void* const* d_in, const int* in_sizes, int n_in,
                              void* d_out, int out_size, void* d_ws, size_t ws_size,
                              hipStream_t stream)
{
    const float* x        = (const float*)d_in[0];
    const float* y        = (const float*)d_in[1];
    const float* w_fc2_t  = (const float*)d_in[12];
    const float* b_fc2_t  = (const float*)d_in[13];
    const float* w_fc2_v  = (const float*)d_in[14];
    const float* b_fc2_v  = (const float*)d_in[15];
    const float* wvec     = (const float*)d_in[18];

    float* xsp = (float*)d_ws;                       // 917504 f32
    float* ysp = xsp + 917504;                       // 917504 f32
    unsigned short* wvb = (unsigned short*)(ysp + 917504);  // 262144 bf16
    unsigned short* wtb = wvb + 262144;              // 262144 bf16

    // 1) softpool (global_load_lds staged) + weight cvt, one launch
    sp_k<<<dim3(M_ROWS + 128, 2), 256, 0, stream>>>(
        x, y, w_fc2_v, w_fc2_t, xsp, ysp, wvb, wtb);
    // 2) fused fc2 + residual + softmax + concat
    gemm_sm_k<<<dim3(M_ROWS/16, 2), 1024, 0, stream>>>(
        xsp, ysp, wvb, wtb, b_fc2_v, b_fc2_t, wvec, (float*)d_out);
}